// Round 2
// baseline (89.010 us; speedup 1.0000x reference)
//
#include <hip/hip_runtime.h>

static __device__ __forceinline__ unsigned umax2(unsigned a, unsigned b) { return a > b ? a : b; }

// One block = 4 waves. One wave = 8 batches = 16 determinants.
// 16 groups of 4 lanes; group g = det g (batch g>>1, half g&1).
// Lane q of a group owns rows 4q..4q+3 of its 16x16 matrix.
//
// Hot path: pivot-free GE (pivot row index == k, statically addressed ->
// no selection tree, no argmax, no sign tracking). Groups that hit a tiny
// pivot (|piv| < 1e-4, ~0.1% of dets) redo with full partial pivoting.
__global__ __launch_bounds__(256, 4) void slater_det_kernel(
    const float* __restrict__ cfg,
    const float* __restrict__ sup,
    const float* __restrict__ sdn,
    float* __restrict__ out)
{
    __shared__ __align__(16) int idx_lds[4][16][16];

    const int tid  = threadIdx.x;
    const int wave = tid >> 6;
    const int lane = tid & 63;
    const int wb0  = (blockIdx.x * 4 + wave) * 8;   // first batch of this wave

    const unsigned long long lt = (1ull << lane) - 1ull;

    // ---------------- Phase 1: sorted indices of the ones (depth-4 pipeline) ----
    float4 c[4];
#pragma unroll
    for (int d = 0; d < 4; ++d) {
        const float* p = cfg + (size_t)(wb0 + (d >> 1)) * 512
                             + (size_t)(d & 1) * 256 + (size_t)lane * 4;
        c[d] = *(const float4*)p;
    }
#pragma unroll
    for (int d = 0; d < 16; ++d) {
        float4 v = c[d & 3];
        if (d + 4 < 16) {
            const int dn = d + 4;
            const float* p = cfg + (size_t)(wb0 + (dn >> 1)) * 512
                                 + (size_t)(dn & 1) * 256 + (size_t)lane * 4;
            c[d & 3] = *(const float4*)p;
        }
        bool n0 = v.x != 0.f, n1 = v.y != 0.f, n2 = v.z != 0.f, n3 = v.w != 0.f;
        unsigned long long b0 = __ballot(n0);
        unsigned long long b1 = __ballot(n1);
        unsigned long long b2 = __ballot(n2);
        unsigned long long b3 = __ballot(n3);
        int base = __popcll(b0 & lt) + __popcll(b1 & lt)
                 + __popcll(b2 & lt) + __popcll(b3 & lt);
        int pos = lane * 4;
        int r = base;
        if (n0 && r < 16) idx_lds[wave][d][r] = pos;
        r += n0;
        if (n1 && r < 16) idx_lds[wave][d][r] = pos + 1;
        r += n1;
        if (n2 && r < 16) idx_lds[wave][d][r] = pos + 2;
        r += n2;
        if (n3 && r < 16) idx_lds[wave][d][r] = pos + 3;
    }
    __syncthreads();

    // ---------------- Phase 2: gather rows + pivot-free GE ----------------------
    const int g = lane >> 2;
    const int q = lane & 3;
    const int4 ri = *(const int4*)&idx_lds[wave][g][q * 4];
    const float* tab = (g & 1) ? sdn : sup;
    const int rid[4] = {ri.x, ri.y, ri.z, ri.w};

    float rr[4][16];
#pragma unroll
    for (int j = 0; j < 4; ++j) {
        const float* p = tab + (size_t)rid[j] * 16;
        float4 a = *(const float4*)(p + 0);
        float4 b = *(const float4*)(p + 4);
        float4 e = *(const float4*)(p + 8);
        float4 f = *(const float4*)(p + 12);
        rr[j][0]=a.x;  rr[j][1]=a.y;  rr[j][2]=a.z;  rr[j][3]=a.w;
        rr[j][4]=b.x;  rr[j][5]=b.y;  rr[j][6]=b.z;  rr[j][7]=b.w;
        rr[j][8]=e.x;  rr[j][9]=e.y;  rr[j][10]=e.z; rr[j][11]=e.w;
        rr[j][12]=f.x; rr[j][13]=f.y; rr[j][14]=f.z; rr[j][15]=f.w;
    }

    const int gbase = lane & ~3;
    float det = 1.f;
    bool bad = false;
#pragma unroll
    for (int k = 0; k < 16; ++k) {
        const int src = gbase | (k >> 2);   // owner lane of pivot row k
        const int jp  = k & 3;              // its static local row index
        float piv = __shfl(rr[jp][k], src);
        det *= piv;
        bad = bad || (fabsf(piv) < 1e-4f);
        float inv = 1.0f / piv;
        float f0 = rr[0][k] * inv;
        float f1 = rr[1][k] * inv;
        float f2 = rr[2][k] * inv;
        float f3 = rr[3][k] * inv;
        // Update all 4 rows unconditionally: rows < k only accumulate garbage
        // that is never read again; row k zeroes itself; rows > k get the
        // correct elimination. Keeps every op exec-uniform and static.
#pragma unroll
        for (int cc = k + 1; cc < 16; ++cc) {
            float pcc = __shfl(rr[jp][cc], src);
            rr[0][cc] = __builtin_fmaf(-f0, pcc, rr[0][cc]);
            rr[1][cc] = __builtin_fmaf(-f1, pcc, rr[1][cc]);
            rr[2][cc] = __builtin_fmaf(-f2, pcc, rr[2][cc]);
            rr[3][cc] = __builtin_fmaf(-f3, pcc, rr[3][cc]);
        }
    }

    // ---------------- Rare fallback: full partial pivoting ----------------------
    // bad is group-uniform (piv identical across the 4 lanes).
    if (__ballot(bad)) {
        if (bad) {
            // reload this group's matrix (L1-hot)
#pragma unroll
            for (int j = 0; j < 4; ++j) {
                const float* p = tab + (size_t)rid[j] * 16;
                float4 a = *(const float4*)(p + 0);
                float4 b = *(const float4*)(p + 4);
                float4 e = *(const float4*)(p + 8);
                float4 f = *(const float4*)(p + 12);
                rr[j][0]=a.x;  rr[j][1]=a.y;  rr[j][2]=a.z;  rr[j][3]=a.w;
                rr[j][4]=b.x;  rr[j][5]=b.y;  rr[j][6]=b.z;  rr[j][7]=b.w;
                rr[j][8]=e.x;  rr[j][9]=e.y;  rr[j][10]=e.z; rr[j][11]=e.w;
                rr[j][12]=f.x; rr[j][13]=f.y; rr[j][14]=f.z; rr[j][15]=f.w;
            }
            unsigned am = 0xFu;
            float fdet = 1.f;
            int flips = 0;
#pragma unroll
            for (int k = 0; k < 16; ++k) {
                unsigned a0 = (__float_as_uint(rr[0][k]) & 0x7FFFFFF0u) | (unsigned)(q*4+0);
                unsigned a1 = (__float_as_uint(rr[1][k]) & 0x7FFFFFF0u) | (unsigned)(q*4+1);
                unsigned a2 = (__float_as_uint(rr[2][k]) & 0x7FFFFFF0u) | (unsigned)(q*4+2);
                unsigned a3 = (__float_as_uint(rr[3][k]) & 0x7FFFFFF0u) | (unsigned)(q*4+3);
                unsigned key0 = (am & 1u) ? a0 : (unsigned)(q*4+0);
                unsigned key1 = (am & 2u) ? a1 : (unsigned)(q*4+1);
                unsigned key2 = (am & 4u) ? a2 : (unsigned)(q*4+2);
                unsigned key3 = (am & 8u) ? a3 : (unsigned)(q*4+3);
                unsigned kloc = umax2(umax2(key0, key1), umax2(key2, key3));
                int jloc = (int)(kloc & 3u);
                float crow[16];
#pragma unroll
                for (int cc = k; cc < 16; ++cc) {
                    float t01 = (jloc & 1) ? rr[1][cc] : rr[0][cc];
                    float t23 = (jloc & 1) ? rr[3][cc] : rr[2][cc];
                    crow[cc] = (jloc & 2) ? t23 : t01;
                }
                unsigned ko = kloc;
                ko = umax2(ko, (unsigned)__shfl_xor((int)ko, 1));
                ko = umax2(ko, (unsigned)__shfl_xor((int)ko, 2));
                int p   = (int)(ko & 15u);
                int src = gbase | (p >> 2);
                float prow[16];
#pragma unroll
                for (int cc = k; cc < 16; ++cc) prow[cc] = __shfl(crow[cc], src);
                float piv = prow[k];
                fdet *= piv;
                int t = p - q * 4;
                unsigned mlt = (t <= 0) ? 0u : ((t >= 4) ? 0xFu : ((1u << t) - 1u));
                int cnt = __popc(am & mlt);
                cnt += __shfl_xor(cnt, 1);
                cnt += __shfl_xor(cnt, 2);
                flips += cnt;
                if (q == (p >> 2)) am &= ~(1u << (p & 3));
                float inv = 1.0f / piv;
                float f0 = rr[0][k] * inv;
                float f1 = rr[1][k] * inv;
                float f2 = rr[2][k] * inv;
                float f3 = rr[3][k] * inv;
#pragma unroll
                for (int cc = k + 1; cc < 16; ++cc) {
                    rr[0][cc] = __builtin_fmaf(-f0, prow[cc], rr[0][cc]);
                    rr[1][cc] = __builtin_fmaf(-f1, prow[cc], rr[1][cc]);
                    rr[2][cc] = __builtin_fmaf(-f2, prow[cc], rr[2][cc]);
                    rr[3][cc] = __builtin_fmaf(-f3, prow[cc], rr[3][cc]);
                }
            }
            det = (flips & 1) ? -fdet : fdet;
        }
    }

    // ---------------- Combine up*down and write ---------------------------------
    // det is identical on all 4 lanes of a group; groups 2b (up) and 2b+1 (down)
    // sit in lanes 8b..8b+3 / 8b+4..8b+7 -> partner is lane^4.
    float prod = det * __shfl_xor(det, 4);
    if ((lane & 7) == 0) out[wb0 + (lane >> 3)] = prod;
}

extern "C" void kernel_launch(void* const* d_in, const int* in_sizes, int n_in,
                              void* d_out, int out_size, void* d_ws, size_t ws_size,
                              hipStream_t stream) {
    const float* cfg = (const float*)d_in[0];
    const float* sup = (const float*)d_in[1];
    const float* sdn = (const float*)d_in[2];
    float* outp = (float*)d_out;
    const int B = in_sizes[0] / 512;          // 131072
    const int blocks = B / 32;                // 8 batches/wave * 4 waves/block
    slater_det_kernel<<<blocks, 256, 0, stream>>>(cfg, sup, sdn, outp);
}

// Round 4
// 67.810 us; speedup vs baseline: 1.3126x; 1.3126x over previous
//
#include <hip/hip_runtime.h>

static __device__ __forceinline__ unsigned umax2(unsigned a, unsigned b) { return a > b ? a : b; }

// ---------------------------------------------------------------------------
// Main kernel. One block = 4 waves; one wave = 8 batches = 16 determinants.
// 16 groups of 4 lanes; group g = det g (batch g>>1, half g&1); lane q owns
// rows 4q..4q+3. Hot path is pivot-free GE (statically-addressed pivot row,
// no selection, no sign tracking). Groups hitting |piv| < 1e-4 enqueue their
// batch into d_ws for a pivoted cleanup kernel (keeps hot-path VGPRs low).
// ---------------------------------------------------------------------------
__global__ __launch_bounds__(256) void slater_det_main(
    const float* __restrict__ cfg,
    const float* __restrict__ sup,
    const float* __restrict__ sdn,
    float* __restrict__ out,
    unsigned* __restrict__ ws_count,
    unsigned* __restrict__ ws_rec,
    unsigned cap)
{
    __shared__ __align__(16) int idx_lds[4][16][16];

    const int tid  = threadIdx.x;
    const int wave = tid >> 6;
    const int lane = tid & 63;
    const int wb0  = (blockIdx.x * 4 + wave) * 8;

    // ---------------- Phase 1: sorted one-positions (all 16 loads in flight) ----
    float4 c[16];
#pragma unroll
    for (int d = 0; d < 16; ++d) {
        const float* p = cfg + (size_t)(wb0 + (d >> 1)) * 512
                             + (size_t)(d & 1) * 256 + (size_t)lane * 4;
        c[d] = *(const float4*)p;
    }
    const unsigned long long lt = (1ull << lane) - 1ull;
#pragma unroll
    for (int d = 0; d < 16; ++d) {
        float4 v = c[d];
        bool n0 = v.x != 0.f, n1 = v.y != 0.f, n2 = v.z != 0.f, n3 = v.w != 0.f;
        unsigned long long b0 = __ballot(n0);
        unsigned long long b1 = __ballot(n1);
        unsigned long long b2 = __ballot(n2);
        unsigned long long b3 = __ballot(n3);
        int base = __popcll(b0 & lt) + __popcll(b1 & lt)
                 + __popcll(b2 & lt) + __popcll(b3 & lt);
        int pos = lane * 4;
        int r = base;
        if (n0 && r < 16) idx_lds[wave][d][r] = pos;
        r += n0;
        if (n1 && r < 16) idx_lds[wave][d][r] = pos + 1;
        r += n1;
        if (n2 && r < 16) idx_lds[wave][d][r] = pos + 2;
        r += n2;
        if (n3 && r < 16) idx_lds[wave][d][r] = pos + 3;
    }
    __syncthreads();

    // ---------------- Phase 2: gather rows + pivot-free GE ----------------------
    const int g = lane >> 2;
    const int q = lane & 3;
    const int4 ri = *(const int4*)&idx_lds[wave][g][q * 4];
    const float* tab = (g & 1) ? sdn : sup;
    const int rid[4] = {ri.x, ri.y, ri.z, ri.w};

    float rr[4][16];
#pragma unroll
    for (int j = 0; j < 4; ++j) {
        const float* p = tab + (size_t)rid[j] * 16;
        float4 a = *(const float4*)(p + 0);
        float4 b = *(const float4*)(p + 4);
        float4 e = *(const float4*)(p + 8);
        float4 f = *(const float4*)(p + 12);
        rr[j][0]=a.x;  rr[j][1]=a.y;  rr[j][2]=a.z;  rr[j][3]=a.w;
        rr[j][4]=b.x;  rr[j][5]=b.y;  rr[j][6]=b.z;  rr[j][7]=b.w;
        rr[j][8]=e.x;  rr[j][9]=e.y;  rr[j][10]=e.z; rr[j][11]=e.w;
        rr[j][12]=f.x; rr[j][13]=f.y; rr[j][14]=f.z; rr[j][15]=f.w;
    }

    const int gbase = lane & ~3;
    float det = 1.f;
    bool bad = false;
#pragma unroll
    for (int k = 0; k < 16; ++k) {
        const int src = gbase | (k >> 2);
        const int jp  = k & 3;
        float piv = __shfl(rr[jp][k], src);
        det *= piv;
        bad = bad || (fabsf(piv) < 1e-4f);
        float inv = __builtin_amdgcn_rcpf(piv);
        float f0 = rr[0][k] * inv;
        float f1 = rr[1][k] * inv;
        float f2 = rr[2][k] * inv;
        float f3 = rr[3][k] * inv;
#pragma unroll
        for (int cc = k + 1; cc < 16; ++cc) {
            float pcc = __shfl(rr[jp][cc], src);
            rr[0][cc] = __builtin_fmaf(-f0, pcc, rr[0][cc]);
            rr[1][cc] = __builtin_fmaf(-f1, pcc, rr[1][cc]);
            rr[2][cc] = __builtin_fmaf(-f2, pcc, rr[2][cc]);
            rr[3][cc] = __builtin_fmaf(-f3, pcc, rr[3][cc]);
        }
    }

    // ---------------- Enqueue bad batches for pivoted cleanup -------------------
    int badflag = bad ? 1 : 0;
    int partnerbad = __shfl_xor(badflag, 4);
    if ((badflag | partnerbad) && (lane & 7) == 0) {   // one writer per batch
        unsigned slot = atomicAdd(ws_count, 1u);
        if (slot < cap) {
            unsigned* rec = ws_rec + slot * 12;
            rec[0] = (unsigned)(wb0 + (lane >> 3));
            const int gU = lane >> 2;                  // even group (up half)
#pragma unroll
            for (int t = 0; t < 4; ++t) {
                const int* iu = &idx_lds[wave][gU][t * 4];
                const int* id = &idx_lds[wave][gU | 1][t * 4];
                rec[1 + t] = (unsigned)iu[0] | ((unsigned)iu[1] << 8)
                           | ((unsigned)iu[2] << 16) | ((unsigned)iu[3] << 24);
                rec[5 + t] = (unsigned)id[0] | ((unsigned)id[1] << 8)
                           | ((unsigned)id[2] << 16) | ((unsigned)id[3] << 24);
            }
        }
    }

    // ---------------- Combine up*down and write ---------------------------------
    float prod = det * __shfl_xor(det, 4);
    if ((lane & 7) == 0) out[wb0 + (lane >> 3)] = prod;
}

// ---------------------------------------------------------------------------
// Cleanup kernel: 8 lanes per batch (lanes 0-3: up det, 4-7: down det), full
// partial pivoting. Grid-stride over the recorded items. Rare (~0.1%).
// ---------------------------------------------------------------------------
__global__ __launch_bounds__(256) void slater_det_cleanup(
    const float* __restrict__ sup,
    const float* __restrict__ sdn,
    float* __restrict__ out,
    const unsigned* __restrict__ ws_count,
    const unsigned* __restrict__ ws_rec,
    unsigned cap)
{
    unsigned n = *ws_count;
    if (n > cap) n = cap;
    const int tid  = blockIdx.x * 256 + threadIdx.x;
    const int unit = tid >> 3;
    const int nunits = (int)(gridDim.x * 256) >> 3;
    const int l8   = threadIdx.x & 7;
    const int wl   = threadIdx.x & 63;
    const int q    = wl & 3;
    const int gbase = wl & ~3;

    for (unsigned item = unit; item < n; item += nunits) {
        const unsigned* rec = ws_rec + item * 12;
        const unsigned batch = rec[0];
        const int half = l8 >> 2;
        const unsigned pk = rec[1 + half * 4 + q];
        const int rid[4] = { (int)(pk & 255u), (int)((pk >> 8) & 255u),
                             (int)((pk >> 16) & 255u), (int)(pk >> 24) };
        const float* tab = half ? sdn : sup;

        float rr[4][16];
#pragma unroll
        for (int j = 0; j < 4; ++j) {
            const float* p = tab + (size_t)rid[j] * 16;
            float4 a = *(const float4*)(p + 0);
            float4 b = *(const float4*)(p + 4);
            float4 e = *(const float4*)(p + 8);
            float4 f = *(const float4*)(p + 12);
            rr[j][0]=a.x;  rr[j][1]=a.y;  rr[j][2]=a.z;  rr[j][3]=a.w;
            rr[j][4]=b.x;  rr[j][5]=b.y;  rr[j][6]=b.z;  rr[j][7]=b.w;
            rr[j][8]=e.x;  rr[j][9]=e.y;  rr[j][10]=e.z; rr[j][11]=e.w;
            rr[j][12]=f.x; rr[j][13]=f.y; rr[j][14]=f.z; rr[j][15]=f.w;
        }

        unsigned am = 0xFu;
        float fdet = 1.f;
        int flips = 0;
#pragma unroll
        for (int k = 0; k < 16; ++k) {
            unsigned a0 = (__float_as_uint(rr[0][k]) & 0x7FFFFFF0u) | (unsigned)(q*4+0);
            unsigned a1 = (__float_as_uint(rr[1][k]) & 0x7FFFFFF0u) | (unsigned)(q*4+1);
            unsigned a2 = (__float_as_uint(rr[2][k]) & 0x7FFFFFF0u) | (unsigned)(q*4+2);
            unsigned a3 = (__float_as_uint(rr[3][k]) & 0x7FFFFFF0u) | (unsigned)(q*4+3);
            unsigned key0 = (am & 1u) ? a0 : (unsigned)(q*4+0);
            unsigned key1 = (am & 2u) ? a1 : (unsigned)(q*4+1);
            unsigned key2 = (am & 4u) ? a2 : (unsigned)(q*4+2);
            unsigned key3 = (am & 8u) ? a3 : (unsigned)(q*4+3);
            unsigned kloc = umax2(umax2(key0, key1), umax2(key2, key3));
            int jloc = (int)(kloc & 3u);
            float crow[16];
#pragma unroll
            for (int cc = k; cc < 16; ++cc) {
                float t01 = (jloc & 1) ? rr[1][cc] : rr[0][cc];
                float t23 = (jloc & 1) ? rr[3][cc] : rr[2][cc];
                crow[cc] = (jloc & 2) ? t23 : t01;
            }
            unsigned ko = kloc;
            ko = umax2(ko, (unsigned)__shfl_xor((int)ko, 1));
            ko = umax2(ko, (unsigned)__shfl_xor((int)ko, 2));
            int p   = (int)(ko & 15u);
            int src = gbase | (p >> 2);
            float prow[16];
#pragma unroll
            for (int cc = k; cc < 16; ++cc) prow[cc] = __shfl(crow[cc], src);
            float piv = prow[k];
            fdet *= piv;
            int t = p - q * 4;
            unsigned mlt = (t <= 0) ? 0u : ((t >= 4) ? 0xFu : ((1u << t) - 1u));
            int cnt = __popc(am & mlt);
            cnt += __shfl_xor(cnt, 1);
            cnt += __shfl_xor(cnt, 2);
            flips += cnt;
            if (q == (p >> 2)) am &= ~(1u << (p & 3));
            float inv = 1.0f / piv;
            float f0 = rr[0][k] * inv;
            float f1 = rr[1][k] * inv;
            float f2 = rr[2][k] * inv;
            float f3 = rr[3][k] * inv;
#pragma unroll
            for (int cc = k + 1; cc < 16; ++cc) {
                rr[0][cc] = __builtin_fmaf(-f0, prow[cc], rr[0][cc]);
                rr[1][cc] = __builtin_fmaf(-f1, prow[cc], rr[1][cc]);
                rr[2][cc] = __builtin_fmaf(-f2, prow[cc], rr[2][cc]);
                rr[3][cc] = __builtin_fmaf(-f3, prow[cc], rr[3][cc]);
            }
        }
        float det = (flips & 1) ? -fdet : fdet;
        float prod = det * __shfl_xor(det, 4);
        if (l8 == 0) out[batch] = prod;
    }
}

extern "C" void kernel_launch(void* const* d_in, const int* in_sizes, int n_in,
                              void* d_out, int out_size, void* d_ws, size_t ws_size,
                              hipStream_t stream) {
    const float* cfg = (const float*)d_in[0];
    const float* sup = (const float*)d_in[1];
    const float* sdn = (const float*)d_in[2];
    float* outp = (float*)d_out;
    unsigned* ws_count = (unsigned*)d_ws;
    unsigned* ws_rec   = (unsigned*)d_ws + 4;            // records at +16B
    unsigned cap = (unsigned)((ws_size - 16) / 48);      // 12 uints per record
    const int B = in_sizes[0] / 512;                     // 131072
    const int blocks = B / 32;

    hipMemsetAsync(d_ws, 0, 16, stream);
    slater_det_main<<<blocks, 256, 0, stream>>>(cfg, sup, sdn, outp,
                                                ws_count, ws_rec, cap);
    slater_det_cleanup<<<16, 256, 0, stream>>>(sup, sdn, outp,
                                               ws_count, ws_rec, cap);
}